// Round 15
// baseline (29.090 us; speedup 1.0000x reference)
//
#include <hip/hip_runtime.h>

// SSIM loss, N=64 images, 1 ch, 384x384 f32, 7x7 box, VALID -> 378x378. out = -mean(S).
//
// R15 = R8 (28.45us best) with per-column math PACKED as f32x2 so the backend
// emits v_pk_{add,mul,fma}_f32 (VOP3P, gfx90a+). Evidence: across R5..R14,
// time ~ total issued wave-insts at fixed ~24% efficiency; occupancy (R13/R14),
// prefetch depth (R12), shuffle batching (R10) all falsified. The remaining
// lever is instruction count: slide/formula/prologue are per-column-independent
// f32 ops on 6 adjacent columns -> 2-wide packing cuts ~30% of VALU insts.
// HSUM (prefix chains + __shfl_down) stays scalar: shuffles are 32-bit ops.
// Everything else R8-verbatim: lane owns cols 6l..6l+5, RB=14, 7-deep f32x2
// history, 2-deep prefetch, rolled kk loop, t34 merge, two-kernel reduction.

constexpr int IND   = 384;
constexpr int OUTD  = 378;
constexpr int RB    = 14;            // output rows per band
constexpr int BANDS = OUTD / RB;     // 27
constexpr int CPL   = 6;             // cols per lane (3 f32x2 groups)

using f32x2 = __attribute__((ext_vector_type(2))) float;

#define FMA2(a, b, c) __builtin_elementwise_fma((a), (b), (c))

__global__ __launch_bounds__(64, 2)
void ssim_band(const float* __restrict__ X, const float* __restrict__ Y,
               const float* __restrict__ MX, float* __restrict__ blocksum)
{
    const int band = blockIdx.x;
    const int n    = blockIdx.y;
    const int lane = threadIdx.x;
    const int c0   = lane * CPL;
    const int r0   = band * RB;      // input rows r0..r0+19, all <= 383

    const float* __restrict__ Xp = X + (size_t)n * (IND * IND) + c0;
    const float* __restrict__ Yp = Y + (size_t)n * (IND * IND) + c0;

    f32x2 hx[7][3], hy[7][3];                    // raw 7-row history (packed)
    f32x2 sx[3]  = {}, sy[3]  = {};
    f32x2 sxx[3] = {}, syy[3] = {}, sxy[3] = {};

#define LOADROW(DX, DY, R) {                                                  \
    const float* _px = Xp + (size_t)(R) * IND;                                \
    const float* _py = Yp + (size_t)(R) * IND;                                \
    DX[0] = *(const f32x2*)_px;                                               \
    DX[1] = *(const f32x2*)(_px + 2);                                         \
    DX[2] = *(const f32x2*)(_px + 4);                                         \
    DY[0] = *(const f32x2*)_py;                                               \
    DY[1] = *(const f32x2*)(_py + 2);                                         \
    DY[2] = *(const f32x2*)(_py + 4); }

    // ---- prologue: rows r0..r0+6 into history, prefetch r0+7, r0+8 ----
#pragma unroll
    for (int k = 0; k < 7; ++k) LOADROW(hx[k], hy[k], r0 + k)

    f32x2 pax[3], pay[3], pbx[3], pby[3];
    LOADROW(pax, pay, r0 + 7)
    LOADROW(pbx, pby, r0 + 8)

#pragma unroll
    for (int k = 0; k < 7; ++k)
#pragma unroll
        for (int g = 0; g < 3; ++g) {
            f32x2 x = hx[k][g], y = hy[k][g];
            sx[g] += x;  sy[g] += y;
            sxx[g] = FMA2(x, x, sxx[g]);
            syy[g] = FMA2(y, y, syy[g]);
            sxy[g] = FMA2(x, y, sxy[g]);
        }

    const float m   = MX[n];
    const float c1s = (0.01f * m) * (0.01f * m);
    const float c2s = (0.03f * m) * (0.03f * m);
    const float k1  = 2401.0f * c1s;     // 49^2 * C1
    const float k2  = 2401.0f * c2s;
    const f32x2 K1  = {k1, k1};
    const f32x2 K2  = {k2, k2};
    const f32x2 CN  = {49.0f / 48.0f, 49.0f / 48.0f};
    const f32x2 CN2 = {2.0f * 49.0f / 48.0f, 2.0f * 49.0f / 48.0f};
    const f32x2 TWO = {2.0f, 2.0f};
    const f32x2 F49 = {49.0f, 49.0f};

    // scalar element view of an f32x2[3] (c is a literal 0..5)
#define EL(S, c) (((c) & 1) ? S[(c) >> 1].y : S[(c) >> 1].x)

    // horizontal sliding sum (scalar, R8-verbatim semantics):
    // O[j] = sum over window cols (6l+j .. 6l+j+6)
#define HSUM(S, O) {                                                          \
    float _n0 = __shfl_down(EL(S,0), 1), _n1 = __shfl_down(EL(S,1), 1);       \
    float _n2 = __shfl_down(EL(S,2), 1), _n3 = __shfl_down(EL(S,3), 1);       \
    float _n4 = __shfl_down(EL(S,4), 1), _n5 = __shfl_down(EL(S,5), 1);       \
    float _t  = ((EL(S,0)+EL(S,1)) + (EL(S,2)+EL(S,3))) + (EL(S,4)+EL(S,5));  \
    O[0] = _t   + _n0;                                                        \
    O[1] = O[0] - EL(S,0) + _n1;                                              \
    O[2] = O[1] - EL(S,1) + _n2;                                              \
    O[3] = O[2] - EL(S,2) + _n3;                                              \
    O[4] = O[3] - EL(S,3) + _n4;                                              \
    O[5] = O[4] - EL(S,4) + _n5; }

    float partial = 0.f;

#pragma unroll 1                       // keep the 7-step body I$-resident
    for (int kk = 0; kk < RB / 7; ++kk) {
#pragma unroll
        for (int i = 0; i < 7; ++i) {
            // ---- horizontal sums + formula for output row r0 + 7*kk + i ----
            float t1[6], t2[6], t34[6], t5[6];
            f32x2 u[3];
#pragma unroll
            for (int g = 0; g < 3; ++g) u[g] = sxx[g] + syy[g];
            HSUM(sx,  t1) HSUM(sy,  t2) HSUM(sxy, t5) HSUM(u, t34)

            if (lane < 63) {
#pragma unroll
                for (int g = 0; g < 3; ++g) {
                    f32x2 T1  = {t1[2*g],  t1[2*g+1]};
                    f32x2 T2  = {t2[2*g],  t2[2*g+1]};
                    f32x2 T5  = {t5[2*g],  t5[2*g+1]};
                    f32x2 T34 = {t34[2*g], t34[2*g+1]};
                    f32x2 pxy = T1 * T2;
                    f32x2 ss  = FMA2(T1, T1, T2 * T2);
                    f32x2 A1  = FMA2(TWO, pxy, K1);
                    f32x2 B1  = ss + K1;
                    f32x2 A2  = FMA2(CN2, FMA2(F49, T5, -pxy), K2);
                    f32x2 B2  = FMA2(CN,  FMA2(F49, T34, -ss), K2);
                    f32x2 num = A1 * A2;
                    f32x2 den = B1 * B2;
                    partial += __fdividef(num.x, den.x)
                             + __fdividef(num.y, den.y);
                }
            }

            // ---- slide: -row(r0+7kk+i) +row(r0+7kk+i+7); refill pipeline ----
#pragma unroll
            for (int g = 0; g < 3; ++g) {
                f32x2 nx = pax[g], ny = pay[g];
                f32x2 ox = hx[i][g], oy = hy[i][g];
                sx[g] += nx - ox;
                sy[g] += ny - oy;
                sxx[g] = FMA2(nx, nx, FMA2(-ox, ox, sxx[g]));
                syy[g] = FMA2(ny, ny, FMA2(-oy, oy, syy[g]));
                sxy[g] = FMA2(nx, ny, FMA2(-ox, oy, sxy[g]));
                hx[i][g] = nx;  hy[i][g] = ny;
                pax[g] = pbx[g]; pay[g] = pby[g];
            }
            int nr = r0 + 7 * kk + i + 9;          // 2 rows ahead
            if (nr > IND - 1) nr = IND - 1;        // tail: harmless clamped load
            LOADROW(pbx, pby, nr)
        }
    }
#undef HSUM
#undef EL
#undef LOADROW

    // ---- wave reduction (deterministic) ----
#pragma unroll
    for (int off = 32; off; off >>= 1) partial += __shfl_down(partial, off);
    if (lane == 0) blocksum[(size_t)n * BANDS + band] = partial;
}

__global__ __launch_bounds__(256)
void ssim_reduce(const float* __restrict__ blocksum, float* __restrict__ out,
                 int nblocks, float inv_npix)
{
    const int tid = threadIdx.x;
    float s = 0.f;
    for (int i = tid; i < nblocks; i += 256) s += blocksum[i];
#pragma unroll
    for (int off = 32; off; off >>= 1) s += __shfl_down(s, off);
    __shared__ float ws[4];
    if ((tid & 63) == 0) ws[tid >> 6] = s;
    __syncthreads();
    if (tid == 0) out[0] = -(ws[0] + ws[1] + ws[2] + ws[3]) * inv_npix;
}

extern "C" void kernel_launch(void* const* d_in, const int* in_sizes, int n_in,
                              void* d_out, int out_size, void* d_ws, size_t ws_size,
                              hipStream_t stream)
{
    const float* X  = (const float*)d_in[0];
    const float* Y  = (const float*)d_in[1];
    // d_in[2] = norm (unused by reference), d_in[4] = w (ones/49, baked in)
    const float* MX = (const float*)d_in[3];

    const int N       = in_sizes[3];             // 64
    const int nblocks = N * BANDS;               // 1728

    float* bs = (float*)d_ws;

    dim3 grid(BANDS, N);
    ssim_band<<<grid, 64, 0, stream>>>(X, Y, MX, bs);

    const float inv_npix = 1.0f / ((float)N * OUTD * OUTD);
    ssim_reduce<<<1, 256, 0, stream>>>(bs, (float*)d_out, nblocks, inv_npix);
}